// Round 2
// baseline (413.354 us; speedup 1.0000x reference)
//
#include <hip/hip_runtime.h>

#define H 4
#define DIN 128
#define DOUT 64
#define EIN 16
#define EOUT 16
#define NEG_SLOPE 0.2f

typedef unsigned short ushortT;

static __device__ __forceinline__ ushortT f2bf(float f) {
  unsigned x = __float_as_uint(f);
  unsigned r = (x + 0x7FFFu + ((x >> 16) & 1u)) >> 16;   // RNE
  return (ushortT)r;
}
static __device__ __forceinline__ float bf2f(ushortT u) {
  return __uint_as_float(((unsigned)u) << 16);
}

// ---------------- node projection + fused alpha_l/alpha_r ------------------
// xlb[N][H][64] bf16 = x[N][128] @ W_l^T ; al/ar[N][H] = (xl*att).sum
// grid: ((N+63)/64, H). Block computes 64 rows x 64 cols (one head).
__global__ __launch_bounds__(256) void k_nodeproj(const float* __restrict__ x,
                                                  const float* __restrict__ Wl,
                                                  const float* __restrict__ att_l,
                                                  const float* __restrict__ att_r,
                                                  ushortT* __restrict__ xlb,
                                                  float* __restrict__ al,
                                                  float* __restrict__ ar, int N) {
  __shared__ float4 As4[64][33];   // [row][k/4]
  __shared__ float Bt[32][68];     // [k within chunk][j], padded
  __shared__ float sl[64][17];
  __shared__ float sr[64][17];
  int tid = threadIdx.x;
  int m0 = blockIdx.x * 64;
  int hb = blockIdx.y;
  int n0 = hb * 64;

  for (int f = tid; f < 64 * 32; f += 256) {
    int r = f >> 5, k4 = f & 31;
    int gr = m0 + r;
    float4 v = make_float4(0.f, 0.f, 0.f, 0.f);
    if (gr < N) v = *(const float4*)(x + (size_t)gr * DIN + k4 * 4);
    As4[r][k4] = v;
  }

  int tm = tid & 15;   // row group
  int tn = tid >> 4;   // col group (16 groups of 4 cols)
  float acc[4][4] = {};

  for (int kc = 0; kc < 4; ++kc) {
    __syncthreads();
    // stage B transposed straight from Wl: Bt[kk][j] = Wl[(n0+j)*128 + kc*32 + kk]
    for (int f = tid; f < 64 * 8; f += 256) {
      int j = f >> 3, kk4 = f & 7;
      float4 v = *(const float4*)(Wl + (size_t)(n0 + j) * DIN + kc * 32 + kk4 * 4);
      Bt[kk4 * 4 + 0][j] = v.x;
      Bt[kk4 * 4 + 1][j] = v.y;
      Bt[kk4 * 4 + 2][j] = v.z;
      Bt[kk4 * 4 + 3][j] = v.w;
    }
    __syncthreads();
#pragma unroll
    for (int kx = 0; kx < 8; ++kx) {
      int kidx = kc * 8 + kx;
      float4 a0 = As4[tm][kidx];
      float4 a1 = As4[tm + 16][kidx];
      float4 a2 = As4[tm + 32][kidx];
      float4 a3 = As4[tm + 48][kidx];
      float4 b0 = *(const float4*)&Bt[kx * 4 + 0][tn * 4];
      float4 b1 = *(const float4*)&Bt[kx * 4 + 1][tn * 4];
      float4 b2 = *(const float4*)&Bt[kx * 4 + 2][tn * 4];
      float4 b3 = *(const float4*)&Bt[kx * 4 + 3][tn * 4];
      const float* av[4] = {&a0.x, &a1.x, &a2.x, &a3.x};
      const float* bv[4] = {&b0.x, &b1.x, &b2.x, &b3.x};
#pragma unroll
      for (int i = 0; i < 4; ++i)
#pragma unroll
        for (int t = 0; t < 4; ++t)
#pragma unroll
          for (int j = 0; j < 4; ++j) acc[i][j] += av[i][t] * bv[t][j];
    }
  }

  // per-thread attention partials + bf16 store
  float attl4[4], attr4[4];
#pragma unroll
  for (int j = 0; j < 4; ++j) {
    attl4[j] = att_l[n0 + tn * 4 + j];
    attr4[j] = att_r[n0 + tn * 4 + j];
  }
#pragma unroll
  for (int i = 0; i < 4; ++i) {
    int r = tm + 16 * i;
    int gr = m0 + r;
    float pl = acc[i][0] * attl4[0] + acc[i][1] * attl4[1] +
               acc[i][2] * attl4[2] + acc[i][3] * attl4[3];
    float pr = acc[i][0] * attr4[0] + acc[i][1] * attr4[1] +
               acc[i][2] * attr4[2] + acc[i][3] * attr4[3];
    sl[r][tn] = pl;
    sr[r][tn] = pr;
    if (gr < N) {
      ushort4 u;
      u.x = f2bf(acc[i][0]); u.y = f2bf(acc[i][1]);
      u.z = f2bf(acc[i][2]); u.w = f2bf(acc[i][3]);
      *(ushort4*)(xlb + (size_t)gr * 256 + hb * 64 + tn * 4) = u;
    }
  }
  __syncthreads();
  if (tid < 64) {
    int gr = m0 + tid;
    if (gr < N) {
      float a = 0.f, b = 0.f;
#pragma unroll
      for (int t = 0; t < 16; ++t) { a += sl[tid][t]; b += sr[tid][t]; }
      al[(size_t)gr * H + hb] = a;
      ar[(size_t)gr * H + hb] = b;
    }
  }
}

// ------- edge GEMM + alpha_e + unnormalized exp + denom + degree hist ------
__global__ __launch_bounds__(256) void k_edgefuse(const float* __restrict__ ea,
                                                  const float* __restrict__ We,
                                                  const float* __restrict__ att_e,
                                                  const float* __restrict__ ebias,
                                                  const int* __restrict__ ei,
                                                  const float* __restrict__ al,
                                                  const float* __restrict__ ar,
                                                  float* __restrict__ eout,
                                                  float* __restrict__ ex,
                                                  float* __restrict__ sden,
                                                  int* __restrict__ cnt, int E) {
  __shared__ float sW[64 * 16];
  __shared__ float sAtt[64];
  __shared__ float sBias[16];
  int tid = threadIdx.x;
  for (int f = tid; f < 64 * 16; f += 256) sW[f] = We[f];
  if (tid < 64) sAtt[tid] = att_e[tid];
  if (tid < 16) sBias[tid] = ebias[tid];
  __syncthreads();
  int e = blockIdx.x * 256 + tid;
  if (e >= E) return;
  float a[16];
  {
    const float4* p = (const float4*)(ea + (size_t)e * EIN);
    float4 v0 = p[0], v1 = p[1], v2 = p[2], v3 = p[3];
    a[0]=v0.x; a[1]=v0.y; a[2]=v0.z; a[3]=v0.w;
    a[4]=v1.x; a[5]=v1.y; a[6]=v1.z; a[7]=v1.w;
    a[8]=v2.x; a[9]=v2.y; a[10]=v2.z; a[11]=v2.w;
    a[12]=v3.x; a[13]=v3.y; a[14]=v3.z; a[15]=v3.w;
  }
  int srcI = ei[e];
  int dstI = ei[E + e];
  float4 al4 = *(const float4*)(al + (size_t)srcI * H);
  float4 ar4 = *(const float4*)(ar + (size_t)dstI * H);
  const float* alp = &al4.x;
  const float* arp = &ar4.x;

  float emax[16];
#pragma unroll
  for (int c = 0; c < 16; ++c) emax[c] = -1e30f;
  float exv[H];
#pragma unroll
  for (int h = 0; h < H; ++h) {
    float acc_ae = 0.f;
#pragma unroll
    for (int c = 0; c < 16; ++c) {
      float s = 0.f;
      const float* wrow = &sW[(h * 16 + c) * 16];
#pragma unroll
      for (int k = 0; k < 16; ++k) s += a[k] * wrow[k];
      acc_ae += s * sAtt[h * 16 + c];
      emax[c] = fmaxf(emax[c], s);
    }
    float lg = alp[h] + arp[h] + acc_ae;
    lg = (lg >= 0.f) ? lg : NEG_SLOPE * lg;
    exv[h] = __expf(lg);
  }
  *(float4*)(ex + (size_t)e * H) = make_float4(exv[0], exv[1], exv[2], exv[3]);
#pragma unroll
  for (int h = 0; h < H; ++h) atomicAdd(&sden[(size_t)dstI * H + h], exv[h]);
  atomicAdd(&cnt[dstI], 1);

  float4 o[4];
#pragma unroll
  for (int q = 0; q < 4; ++q) {
    o[q] = make_float4(fmaxf(emax[q*4+0] + sBias[q*4+0], 0.f),
                       fmaxf(emax[q*4+1] + sBias[q*4+1], 0.f),
                       fmaxf(emax[q*4+2] + sBias[q*4+2], 0.f),
                       fmaxf(emax[q*4+3] + sBias[q*4+3], 0.f));
  }
  float4* op = (float4*)(eout + (size_t)e * EOUT);
  op[0]=o[0]; op[1]=o[1]; op[2]=o[2]; op[3]=o[3];
}

// ---------------- scans ----------------------------------------------------
__global__ __launch_bounds__(256) void k_scan1(const int* __restrict__ cnt,
                                               int* __restrict__ offs,
                                               int* __restrict__ bsum, int N) {
  __shared__ int s[256];
  int i = blockIdx.x * 256 + threadIdx.x;
  int v = (i < N) ? cnt[i] : 0;
  s[threadIdx.x] = v;
  __syncthreads();
  for (int off = 1; off < 256; off <<= 1) {
    int t = (threadIdx.x >= off) ? s[threadIdx.x - off] : 0;
    __syncthreads();
    s[threadIdx.x] += t;
    __syncthreads();
  }
  if (i < N) offs[i] = s[threadIdx.x] - v;
  if (threadIdx.x == 255) bsum[blockIdx.x] = s[255];
}

__global__ __launch_bounds__(256) void k_scan2(const int* __restrict__ bsum,
                                               int* __restrict__ boffs, int NB) {
  __shared__ int s[256];
  int v = (threadIdx.x < NB) ? bsum[threadIdx.x] : 0;
  s[threadIdx.x] = v;
  __syncthreads();
  for (int off = 1; off < 256; off <<= 1) {
    int t = (threadIdx.x >= off) ? s[threadIdx.x - off] : 0;
    __syncthreads();
    s[threadIdx.x] += t;
    __syncthreads();
  }
  if (threadIdx.x < NB) boffs[threadIdx.x] = s[threadIdx.x] - v;
}

__global__ __launch_bounds__(256) void k_scan3(int* __restrict__ offs,
                                               const int* __restrict__ boffs,
                                               int* __restrict__ cursor, int N) {
  int i = blockIdx.x * 256 + threadIdx.x;
  if (i < N) {
    int o = offs[i] + boffs[blockIdx.x];
    offs[i] = o;
    cursor[i] = o;
  }
}

// -------- scatter + CSR reorder of (src, ex) so k_agg reads sequentially ---
__global__ __launch_bounds__(256) void k_scatter(const int* __restrict__ ei,
                                                 const float* __restrict__ ex,
                                                 int* __restrict__ cursor,
                                                 int* __restrict__ ssrc,
                                                 float* __restrict__ sex, int E) {
  int e = blockIdx.x * 256 + threadIdx.x;
  if (e < E) {
    int d = ei[E + e];
    int p = atomicAdd(&cursor[d], 1);
    ssrc[p] = ei[e];
    *(float4*)(sex + (size_t)p * H) = *(const float4*)(ex + (size_t)e * H);
  }
}

// ---------------- aggregation: wave per node, bf16 gather ------------------
__global__ __launch_bounds__(256) void k_agg(const ushortT* __restrict__ xlb,
                                             const int* __restrict__ ssrc,
                                             const float* __restrict__ sex,
                                             const int* __restrict__ offs,
                                             const int* __restrict__ cnt,
                                             const float* __restrict__ sden,
                                             const float* __restrict__ nbias,
                                             float* __restrict__ out, int N) {
  int wv = (blockIdx.x * 256 + threadIdx.x) >> 6;
  int lane = threadIdx.x & 63;
  if (wv >= N) return;
  int deg = cnt[wv];
  int start = offs[wv];
  float acc0 = 0.f, acc1 = 0.f, acc2 = 0.f, acc3 = 0.f;

  int i = 0;
  for (; i + 1 < deg; i += 2) {
    int s0 = ssrc[start + i];
    int s1 = ssrc[start + i + 1];
    float4 e0 = *(const float4*)(sex + (size_t)(start + i) * H);
    float4 e1 = *(const float4*)(sex + (size_t)(start + i + 1) * H);
    const ushortT* p0 = xlb + (size_t)s0 * 256 + lane;
    const ushortT* p1 = xlb + (size_t)s1 * 256 + lane;
    float x00 = bf2f(p0[0]),  x01 = bf2f(p0[64]),
          x02 = bf2f(p0[128]), x03 = bf2f(p0[192]);
    float x10 = bf2f(p1[0]),  x11 = bf2f(p1[64]),
          x12 = bf2f(p1[128]), x13 = bf2f(p1[192]);
    acc0 += e0.x * x00 + e1.x * x10;
    acc1 += e0.y * x01 + e1.y * x11;
    acc2 += e0.z * x02 + e1.z * x12;
    acc3 += e0.w * x03 + e1.w * x13;
  }
  if (i < deg) {
    int s0 = ssrc[start + i];
    float4 e0 = *(const float4*)(sex + (size_t)(start + i) * H);
    const ushortT* p0 = xlb + (size_t)s0 * 256 + lane;
    acc0 += e0.x * bf2f(p0[0]);
    acc1 += e0.y * bf2f(p0[64]);
    acc2 += e0.z * bf2f(p0[128]);
    acc3 += e0.w * bf2f(p0[192]);
  }
  float4 s4 = *(const float4*)(sden + (size_t)wv * H);
  float best = acc0 / (s4.x + 1e-16f);
  best = fmaxf(best, acc1 / (s4.y + 1e-16f));
  best = fmaxf(best, acc2 / (s4.z + 1e-16f));
  best = fmaxf(best, acc3 / (s4.w + 1e-16f));
  out[(size_t)wv * DOUT + lane] = fmaxf(best + nbias[lane], 0.f);
}

// ---------------- launcher -------------------------------------------------
extern "C" void kernel_launch(void* const* d_in, const int* in_sizes, int n_in,
                              void* d_out, int out_size, void* d_ws, size_t ws_size,
                              hipStream_t stream) {
  const float* x     = (const float*)d_in[0];
  const float* ea    = (const float*)d_in[1];
  const int*   ei    = (const int*)d_in[2];
  const float* Wl    = (const float*)d_in[3];
  const float* We    = (const float*)d_in[4];
  const float* att_l = (const float*)d_in[5];
  const float* att_r = (const float*)d_in[6];
  const float* att_e = (const float*)d_in[7];
  const float* nbias = (const float*)d_in[8];
  const float* ebias = (const float*)d_in[9];

  int N = in_sizes[0] / DIN;
  int E = in_sizes[1] / EIN;

  float* out  = (float*)d_out;
  float* eout = (float*)d_out + (size_t)N * DOUT;

  char* w = (char*)d_ws;
  auto alloc = [&](size_t bytes) -> void* {
    void* p = (void*)w;
    w += (bytes + 255) & ~(size_t)255;
    return p;
  };
  ushortT* xlb = (ushortT*)alloc((size_t)N * 256 * 2);
  float* al    = (float*)alloc((size_t)N * H * 4);
  float* ar    = (float*)alloc((size_t)N * H * 4);
  float* ex    = (float*)alloc((size_t)E * H * 4);
  float* sden  = (float*)alloc((size_t)N * H * 4);
  int* cnt     = (int*)alloc((size_t)N * 4);
  int* offs    = (int*)alloc((size_t)N * 4);
  int* cur     = (int*)alloc((size_t)N * 4);
  int* bsum    = (int*)alloc(256 * 4);
  int* boffs   = (int*)alloc(256 * 4);
  int* ssrc    = (int*)alloc((size_t)E * 4);
  float* sex   = (float*)alloc((size_t)E * H * 4);

  hipMemsetAsync(cnt, 0, (size_t)N * 4, stream);
  hipMemsetAsync(sden, 0, (size_t)N * H * 4, stream);

  dim3 gnp((N + 63) / 64, H);
  k_nodeproj<<<gnp, 256, 0, stream>>>(x, Wl, att_l, att_r, xlb, al, ar, N);
  k_edgefuse<<<(E + 255) / 256, 256, 0, stream>>>(ea, We, att_e, ebias, ei, al, ar,
                                                  eout, ex, sden, cnt, E);
  int NB = (N + 255) / 256;
  k_scan1<<<NB, 256, 0, stream>>>(cnt, offs, bsum, N);
  k_scan2<<<1, 256, 0, stream>>>(bsum, boffs, NB);
  k_scan3<<<NB, 256, 0, stream>>>(offs, boffs, cur, N);
  k_scatter<<<(E + 255) / 256, 256, 0, stream>>>(ei, ex, cur, ssrc, sex, E);
  k_agg<<<(N * 64 + 255) / 256, 256, 0, stream>>>(xlb, ssrc, sex, offs, cnt, sden,
                                                  nbias, out, N);
}

// Round 3
// 305.674 us; speedup vs baseline: 1.3523x; 1.3523x over previous
//
#include <hip/hip_runtime.h>

#define H 4
#define DIN 128
#define DOUT 64
#define EIN 16
#define EOUT 16
#define NEG_SLOPE 0.2f

typedef unsigned short ushortT;

static __device__ __forceinline__ ushortT f2bf(float f) {
  unsigned x = __float_as_uint(f);
  unsigned r = (x + 0x7FFFu + ((x >> 16) & 1u)) >> 16;   // RNE
  return (ushortT)r;
}
static __device__ __forceinline__ float bf2f(ushortT u) {
  return __uint_as_float(((unsigned)u) << 16);
}

// ---------------- node projection + fused alpha_l/alpha_r ------------------
// xlb[N][H][64] bf16 = x[N][128] @ W_l^T ; al/ar[N][H] = (xl*att).sum
// grid: ((N+63)/64, H). Block computes 64 rows x 64 cols (one head).
__global__ __launch_bounds__(256) void k_nodeproj(const float* __restrict__ x,
                                                  const float* __restrict__ Wl,
                                                  const float* __restrict__ att_l,
                                                  const float* __restrict__ att_r,
                                                  ushortT* __restrict__ xlb,
                                                  float* __restrict__ al,
                                                  float* __restrict__ ar, int N) {
  __shared__ float4 As4[64][33];   // [row][k/4]
  __shared__ float Bt[32][68];     // [k within chunk][j], padded
  __shared__ float sl[64][17];
  __shared__ float sr[64][17];
  int tid = threadIdx.x;
  int m0 = blockIdx.x * 64;
  int hb = blockIdx.y;
  int n0 = hb * 64;

  for (int f = tid; f < 64 * 32; f += 256) {
    int r = f >> 5, k4 = f & 31;
    int gr = m0 + r;
    float4 v = make_float4(0.f, 0.f, 0.f, 0.f);
    if (gr < N) v = *(const float4*)(x + (size_t)gr * DIN + k4 * 4);
    As4[r][k4] = v;
  }

  int tm = tid & 15;   // row group
  int tn = tid >> 4;   // col group (16 groups of 4 cols)
  float acc[4][4] = {};

  for (int kc = 0; kc < 4; ++kc) {
    __syncthreads();
    // stage B transposed straight from Wl: Bt[kk][j] = Wl[(n0+j)*128 + kc*32 + kk]
    for (int f = tid; f < 64 * 8; f += 256) {
      int j = f >> 3, kk4 = f & 7;
      float4 v = *(const float4*)(Wl + (size_t)(n0 + j) * DIN + kc * 32 + kk4 * 4);
      Bt[kk4 * 4 + 0][j] = v.x;
      Bt[kk4 * 4 + 1][j] = v.y;
      Bt[kk4 * 4 + 2][j] = v.z;
      Bt[kk4 * 4 + 3][j] = v.w;
    }
    __syncthreads();
#pragma unroll
    for (int kx = 0; kx < 8; ++kx) {
      int kidx = kc * 8 + kx;
      float4 a0 = As4[tm][kidx];
      float4 a1 = As4[tm + 16][kidx];
      float4 a2 = As4[tm + 32][kidx];
      float4 a3 = As4[tm + 48][kidx];
      float4 b0 = *(const float4*)&Bt[kx * 4 + 0][tn * 4];
      float4 b1 = *(const float4*)&Bt[kx * 4 + 1][tn * 4];
      float4 b2 = *(const float4*)&Bt[kx * 4 + 2][tn * 4];
      float4 b3 = *(const float4*)&Bt[kx * 4 + 3][tn * 4];
      const float* av[4] = {&a0.x, &a1.x, &a2.x, &a3.x};
      const float* bv[4] = {&b0.x, &b1.x, &b2.x, &b3.x};
#pragma unroll
      for (int i = 0; i < 4; ++i)
#pragma unroll
        for (int t = 0; t < 4; ++t)
#pragma unroll
          for (int j = 0; j < 4; ++j) acc[i][j] += av[i][t] * bv[t][j];
    }
  }

  // per-thread attention partials + bf16 store
  float attl4[4], attr4[4];
#pragma unroll
  for (int j = 0; j < 4; ++j) {
    attl4[j] = att_l[n0 + tn * 4 + j];
    attr4[j] = att_r[n0 + tn * 4 + j];
  }
#pragma unroll
  for (int i = 0; i < 4; ++i) {
    int r = tm + 16 * i;
    int gr = m0 + r;
    float pl = acc[i][0] * attl4[0] + acc[i][1] * attl4[1] +
               acc[i][2] * attl4[2] + acc[i][3] * attl4[3];
    float pr = acc[i][0] * attr4[0] + acc[i][1] * attr4[1] +
               acc[i][2] * attr4[2] + acc[i][3] * attr4[3];
    sl[r][tn] = pl;
    sr[r][tn] = pr;
    if (gr < N) {
      ushort4 u;
      u.x = f2bf(acc[i][0]); u.y = f2bf(acc[i][1]);
      u.z = f2bf(acc[i][2]); u.w = f2bf(acc[i][3]);
      *(ushort4*)(xlb + (size_t)gr * 256 + hb * 64 + tn * 4) = u;
    }
  }
  __syncthreads();
  if (tid < 64) {
    int gr = m0 + tid;
    if (gr < N) {
      float a = 0.f, b = 0.f;
#pragma unroll
      for (int t = 0; t < 16; ++t) { a += sl[tid][t]; b += sr[tid][t]; }
      al[(size_t)gr * H + hb] = a;
      ar[(size_t)gr * H + hb] = b;
    }
  }
}

// ------- edge GEMM + alpha_e + unnormalized exp + e_out (NO atomics) -------
__global__ __launch_bounds__(256) void k_edgecomp(const float* __restrict__ ea,
                                                  const float* __restrict__ We,
                                                  const float* __restrict__ att_e,
                                                  const float* __restrict__ ebias,
                                                  const int* __restrict__ ei,
                                                  const float* __restrict__ al,
                                                  const float* __restrict__ ar,
                                                  float* __restrict__ eout,
                                                  float* __restrict__ ex, int E) {
  __shared__ float sW[64 * 16];
  __shared__ float sAtt[64];
  __shared__ float sBias[16];
  int tid = threadIdx.x;
  for (int f = tid; f < 64 * 16; f += 256) sW[f] = We[f];
  if (tid < 64) sAtt[tid] = att_e[tid];
  if (tid < 16) sBias[tid] = ebias[tid];
  __syncthreads();
  int e = blockIdx.x * 256 + tid;
  if (e >= E) return;
  float a[16];
  {
    const float4* p = (const float4*)(ea + (size_t)e * EIN);
    float4 v0 = p[0], v1 = p[1], v2 = p[2], v3 = p[3];
    a[0]=v0.x; a[1]=v0.y; a[2]=v0.z; a[3]=v0.w;
    a[4]=v1.x; a[5]=v1.y; a[6]=v1.z; a[7]=v1.w;
    a[8]=v2.x; a[9]=v2.y; a[10]=v2.z; a[11]=v2.w;
    a[12]=v3.x; a[13]=v3.y; a[14]=v3.z; a[15]=v3.w;
  }
  int srcI = ei[e];
  int dstI = ei[E + e];
  float4 al4 = *(const float4*)(al + (size_t)srcI * H);
  float4 ar4 = *(const float4*)(ar + (size_t)dstI * H);
  const float* alp = &al4.x;
  const float* arp = &ar4.x;

  float emax[16];
#pragma unroll
  for (int c = 0; c < 16; ++c) emax[c] = -1e30f;
  float exv[H];
#pragma unroll
  for (int h = 0; h < H; ++h) {
    float acc_ae = 0.f;
#pragma unroll
    for (int c = 0; c < 16; ++c) {
      float s = 0.f;
      const float* wrow = &sW[(h * 16 + c) * 16];
#pragma unroll
      for (int k = 0; k < 16; ++k) s += a[k] * wrow[k];
      acc_ae += s * sAtt[h * 16 + c];
      emax[c] = fmaxf(emax[c], s);
    }
    float lg = alp[h] + arp[h] + acc_ae;
    lg = (lg >= 0.f) ? lg : NEG_SLOPE * lg;
    exv[h] = __expf(lg);
  }
  *(float4*)(ex + (size_t)e * H) = make_float4(exv[0], exv[1], exv[2], exv[3]);

  float4 o[4];
#pragma unroll
  for (int q = 0; q < 4; ++q) {
    o[q] = make_float4(fmaxf(emax[q*4+0] + sBias[q*4+0], 0.f),
                       fmaxf(emax[q*4+1] + sBias[q*4+1], 0.f),
                       fmaxf(emax[q*4+2] + sBias[q*4+2], 0.f),
                       fmaxf(emax[q*4+3] + sBias[q*4+3], 0.f));
  }
  float4* op = (float4*)(eout + (size_t)e * EOUT);
  op[0]=o[0]; op[1]=o[1]; op[2]=o[2]; op[3]=o[3];
}

// ---------------- degree histogram (int atomics only) ----------------------
__global__ __launch_bounds__(256) void k_hist(const int* __restrict__ ei,
                                              int* __restrict__ cnt, int E) {
  int e = blockIdx.x * 256 + threadIdx.x;
  if (e < E) atomicAdd(&cnt[ei[E + e]], 1);
}

// ---------------- scans ----------------------------------------------------
__global__ __launch_bounds__(256) void k_scan1(const int* __restrict__ cnt,
                                               int* __restrict__ offs,
                                               int* __restrict__ bsum, int N) {
  __shared__ int s[256];
  int i = blockIdx.x * 256 + threadIdx.x;
  int v = (i < N) ? cnt[i] : 0;
  s[threadIdx.x] = v;
  __syncthreads();
  for (int off = 1; off < 256; off <<= 1) {
    int t = (threadIdx.x >= off) ? s[threadIdx.x - off] : 0;
    __syncthreads();
    s[threadIdx.x] += t;
    __syncthreads();
  }
  if (i < N) offs[i] = s[threadIdx.x] - v;
  if (threadIdx.x == 255) bsum[blockIdx.x] = s[255];
}

__global__ __launch_bounds__(256) void k_scan2(const int* __restrict__ bsum,
                                               int* __restrict__ boffs, int NB) {
  __shared__ int s[256];
  int v = (threadIdx.x < NB) ? bsum[threadIdx.x] : 0;
  s[threadIdx.x] = v;
  __syncthreads();
  for (int off = 1; off < 256; off <<= 1) {
    int t = (threadIdx.x >= off) ? s[threadIdx.x - off] : 0;
    __syncthreads();
    s[threadIdx.x] += t;
    __syncthreads();
  }
  if (threadIdx.x < NB) boffs[threadIdx.x] = s[threadIdx.x] - v;
}

__global__ __launch_bounds__(256) void k_scan3(int* __restrict__ offs,
                                               const int* __restrict__ boffs,
                                               int* __restrict__ cursor, int N) {
  int i = blockIdx.x * 256 + threadIdx.x;
  if (i < N) {
    int o = offs[i] + boffs[blockIdx.x];
    offs[i] = o;
    cursor[i] = o;
  }
}

// -------- scatter + CSR reorder of (src, ex) so k_agg reads sequentially ---
__global__ __launch_bounds__(256) void k_scatter(const int* __restrict__ ei,
                                                 const float* __restrict__ ex,
                                                 int* __restrict__ cursor,
                                                 int* __restrict__ ssrc,
                                                 float* __restrict__ sex, int E) {
  int e = blockIdx.x * 256 + threadIdx.x;
  if (e < E) {
    int d = ei[E + e];
    int p = atomicAdd(&cursor[d], 1);
    ssrc[p] = ei[e];
    *(float4*)(sex + (size_t)p * H) = *(const float4*)(ex + (size_t)e * H);
  }
}

// ------- aggregation: wave per node, bf16 gather, inline denominator -------
__global__ __launch_bounds__(256) void k_agg(const ushortT* __restrict__ xlb,
                                             const int* __restrict__ ssrc,
                                             const float* __restrict__ sex,
                                             const int* __restrict__ offs,
                                             const int* __restrict__ cnt,
                                             const float* __restrict__ nbias,
                                             float* __restrict__ out, int N) {
  int wv = (blockIdx.x * 256 + threadIdx.x) >> 6;
  int lane = threadIdx.x & 63;
  if (wv >= N) return;
  int deg = cnt[wv];
  int start = offs[wv];
  float acc0 = 0.f, acc1 = 0.f, acc2 = 0.f, acc3 = 0.f;
  float s0 = 0.f, s1 = 0.f, s2 = 0.f, s3 = 0.f;

  int i = 0;
  for (; i + 1 < deg; i += 2) {
    int sA = ssrc[start + i];
    int sB = ssrc[start + i + 1];
    float4 e0 = *(const float4*)(sex + (size_t)(start + i) * H);
    float4 e1 = *(const float4*)(sex + (size_t)(start + i + 1) * H);
    const ushortT* p0 = xlb + (size_t)sA * 256 + lane;
    const ushortT* p1 = xlb + (size_t)sB * 256 + lane;
    float x00 = bf2f(p0[0]),  x01 = bf2f(p0[64]),
          x02 = bf2f(p0[128]), x03 = bf2f(p0[192]);
    float x10 = bf2f(p1[0]),  x11 = bf2f(p1[64]),
          x12 = bf2f(p1[128]), x13 = bf2f(p1[192]);
    acc0 += e0.x * x00 + e1.x * x10;
    acc1 += e0.y * x01 + e1.y * x11;
    acc2 += e0.z * x02 + e1.z * x12;
    acc3 += e0.w * x03 + e1.w * x13;
    s0 += e0.x + e1.x;
    s1 += e0.y + e1.y;
    s2 += e0.z + e1.z;
    s3 += e0.w + e1.w;
  }
  if (i < deg) {
    int sA = ssrc[start + i];
    float4 e0 = *(const float4*)(sex + (size_t)(start + i) * H);
    const ushortT* p0 = xlb + (size_t)sA * 256 + lane;
    acc0 += e0.x * bf2f(p0[0]);
    acc1 += e0.y * bf2f(p0[64]);
    acc2 += e0.z * bf2f(p0[128]);
    acc3 += e0.w * bf2f(p0[192]);
    s0 += e0.x; s1 += e0.y; s2 += e0.z; s3 += e0.w;
  }
  float best = acc0 / (s0 + 1e-16f);
  best = fmaxf(best, acc1 / (s1 + 1e-16f));
  best = fmaxf(best, acc2 / (s2 + 1e-16f));
  best = fmaxf(best, acc3 / (s3 + 1e-16f));
  out[(size_t)wv * DOUT + lane] = fmaxf(best + nbias[lane], 0.f);
}

// ---------------- launcher -------------------------------------------------
extern "C" void kernel_launch(void* const* d_in, const int* in_sizes, int n_in,
                              void* d_out, int out_size, void* d_ws, size_t ws_size,
                              hipStream_t stream) {
  const float* x     = (const float*)d_in[0];
  const float* ea    = (const float*)d_in[1];
  const int*   ei    = (const int*)d_in[2];
  const float* Wl    = (const float*)d_in[3];
  const float* We    = (const float*)d_in[4];
  const float* att_l = (const float*)d_in[5];
  const float* att_r = (const float*)d_in[6];
  const float* att_e = (const float*)d_in[7];
  const float* nbias = (const float*)d_in[8];
  const float* ebias = (const float*)d_in[9];

  int N = in_sizes[0] / DIN;
  int E = in_sizes[1] / EIN;

  float* out  = (float*)d_out;
  float* eout = (float*)d_out + (size_t)N * DOUT;

  char* w = (char*)d_ws;
  auto alloc = [&](size_t bytes) -> void* {
    void* p = (void*)w;
    w += (bytes + 255) & ~(size_t)255;
    return p;
  };
  ushortT* xlb = (ushortT*)alloc((size_t)N * 256 * 2);
  float* al    = (float*)alloc((size_t)N * H * 4);
  float* ar    = (float*)alloc((size_t)N * H * 4);
  float* ex    = (float*)alloc((size_t)E * H * 4);
  int* cnt     = (int*)alloc((size_t)N * 4);
  int* offs    = (int*)alloc((size_t)N * 4);
  int* cur     = (int*)alloc((size_t)N * 4);
  int* bsum    = (int*)alloc(256 * 4);
  int* boffs   = (int*)alloc(256 * 4);
  int* ssrc    = (int*)alloc((size_t)E * 4);
  float* sex   = (float*)alloc((size_t)E * H * 4);

  hipMemsetAsync(cnt, 0, (size_t)N * 4, stream);

  dim3 gnp((N + 63) / 64, H);
  k_nodeproj<<<gnp, 256, 0, stream>>>(x, Wl, att_l, att_r, xlb, al, ar, N);
  k_edgecomp<<<(E + 255) / 256, 256, 0, stream>>>(ea, We, att_e, ebias, ei, al, ar,
                                                  eout, ex, E);
  k_hist<<<(E + 255) / 256, 256, 0, stream>>>(ei, cnt, E);
  int NB = (N + 255) / 256;
  k_scan1<<<NB, 256, 0, stream>>>(cnt, offs, bsum, N);
  k_scan2<<<1, 256, 0, stream>>>(bsum, boffs, NB);
  k_scan3<<<NB, 256, 0, stream>>>(offs, boffs, cur, N);
  k_scatter<<<(E + 255) / 256, 256, 0, stream>>>(ei, ex, cur, ssrc, sex, E);
  k_agg<<<(N * 64 + 255) / 256, 256, 0, stream>>>(xlb, ssrc, sex, offs, cnt,
                                                  nbias, out, N);
}

// Round 4
// 258.249 us; speedup vs baseline: 1.6006x; 1.1836x over previous
//
#include <hip/hip_runtime.h>

#define H 4
#define DIN 128
#define DOUT 64
#define EIN 16
#define EOUT 16
#define NEG_SLOPE 0.2f

typedef unsigned short ushortT;
typedef __attribute__((ext_vector_type(4))) short bf16x4;
typedef __attribute__((ext_vector_type(4))) float f32x4;

static __device__ __forceinline__ ushortT f2bf(float f) {
  unsigned x = __float_as_uint(f);
  unsigned r = (x + 0x7FFFu + ((x >> 16) & 1u)) >> 16;   // RNE
  return (ushortT)r;
}

static __device__ __forceinline__ bf16x4 pack4(float4 v) {
  bf16x4 r;
  r[0] = (short)f2bf(v.x);
  r[1] = (short)f2bf(v.y);
  r[2] = (short)f2bf(v.z);
  r[3] = (short)f2bf(v.w);
  return r;
}

#if __has_builtin(__builtin_amdgcn_mfma_f32_16x16x16bf16_1k)
static __device__ __forceinline__ f32x4 mfma16(bf16x4 a, bf16x4 b, f32x4 c) {
  return __builtin_amdgcn_mfma_f32_16x16x16bf16_1k(a, b, c, 0, 0, 0);
}
#else
static __device__ __forceinline__ f32x4 mfma16(bf16x4 a, bf16x4 b, f32x4 c) {
  f32x4 d;
  asm volatile("v_mfma_f32_16x16x16_bf16 %0, %1, %2, %3"
               : "=v"(d) : "v"(a), "v"(b), "v"(c));
  return d;
}
#endif

// ---------------- node projection + fused alpha_l/alpha_r ------------------
// xlb[N][64 chan][4 heads] bf16 ; al/ar[N][H]
__global__ __launch_bounds__(256) void k_nodeproj(const float* __restrict__ x,
                                                  const float* __restrict__ Wl,
                                                  const float* __restrict__ att_l,
                                                  const float* __restrict__ att_r,
                                                  ushortT* __restrict__ xlb,
                                                  float* __restrict__ al,
                                                  float* __restrict__ ar, int N) {
  __shared__ float4 As4[64][33];   // [row][k/4]
  __shared__ float Bt[32][68];     // [k within chunk][j], padded
  __shared__ float sl[64][17];
  __shared__ float sr[64][17];
  int tid = threadIdx.x;
  int m0 = blockIdx.x * 64;
  int hb = blockIdx.y;
  int n0 = hb * 64;

  for (int f = tid; f < 64 * 32; f += 256) {
    int r = f >> 5, k4 = f & 31;
    int gr = m0 + r;
    float4 v = make_float4(0.f, 0.f, 0.f, 0.f);
    if (gr < N) v = *(const float4*)(x + (size_t)gr * DIN + k4 * 4);
    As4[r][k4] = v;
  }

  int tm = tid & 15;
  int tn = tid >> 4;
  float acc[4][4] = {};

  for (int kc = 0; kc < 4; ++kc) {
    __syncthreads();
    for (int f = tid; f < 64 * 8; f += 256) {
      int j = f >> 3, kk4 = f & 7;
      float4 v = *(const float4*)(Wl + (size_t)(n0 + j) * DIN + kc * 32 + kk4 * 4);
      Bt[kk4 * 4 + 0][j] = v.x;
      Bt[kk4 * 4 + 1][j] = v.y;
      Bt[kk4 * 4 + 2][j] = v.z;
      Bt[kk4 * 4 + 3][j] = v.w;
    }
    __syncthreads();
#pragma unroll
    for (int kx = 0; kx < 8; ++kx) {
      int kidx = kc * 8 + kx;
      float4 a0 = As4[tm][kidx];
      float4 a1 = As4[tm + 16][kidx];
      float4 a2 = As4[tm + 32][kidx];
      float4 a3 = As4[tm + 48][kidx];
      float4 b0 = *(const float4*)&Bt[kx * 4 + 0][tn * 4];
      float4 b1 = *(const float4*)&Bt[kx * 4 + 1][tn * 4];
      float4 b2 = *(const float4*)&Bt[kx * 4 + 2][tn * 4];
      float4 b3 = *(const float4*)&Bt[kx * 4 + 3][tn * 4];
      const float* av[4] = {&a0.x, &a1.x, &a2.x, &a3.x};
      const float* bv[4] = {&b0.x, &b1.x, &b2.x, &b3.x};
#pragma unroll
      for (int i = 0; i < 4; ++i)
#pragma unroll
        for (int t = 0; t < 4; ++t)
#pragma unroll
          for (int j = 0; j < 4; ++j) acc[i][j] += av[i][t] * bv[t][j];
    }
  }

  float attl4[4], attr4[4];
#pragma unroll
  for (int j = 0; j < 4; ++j) {
    attl4[j] = att_l[n0 + tn * 4 + j];
    attr4[j] = att_r[n0 + tn * 4 + j];
  }
#pragma unroll
  for (int i = 0; i < 4; ++i) {
    int r = tm + 16 * i;
    int gr = m0 + r;
    float pl = acc[i][0] * attl4[0] + acc[i][1] * attl4[1] +
               acc[i][2] * attl4[2] + acc[i][3] * attl4[3];
    float pr = acc[i][0] * attr4[0] + acc[i][1] * attr4[1] +
               acc[i][2] * attr4[2] + acc[i][3] * attr4[3];
    sl[r][tn] = pl;
    sr[r][tn] = pr;
    if (gr < N) {
      // layout: [node][chan][head]
#pragma unroll
      for (int j = 0; j < 4; ++j)
        xlb[(size_t)gr * 256 + (tn * 4 + j) * 4 + hb] = f2bf(acc[i][j]);
    }
  }
  __syncthreads();
  if (tid < 64) {
    int gr = m0 + tid;
    if (gr < N) {
      float a = 0.f, b = 0.f;
#pragma unroll
      for (int t = 0; t < 16; ++t) { a += sl[tid][t]; b += sr[tid][t]; }
      al[(size_t)gr * H + hb] = a;
      ar[(size_t)gr * H + hb] = b;
    }
  }
}

// ---------------- Wfold[h][k] = sum_c We[h*16+c][k] * att_e[h*16+c] --------
__global__ __launch_bounds__(64) void k_setup(const float* __restrict__ We,
                                              const float* __restrict__ att_e,
                                              float* __restrict__ Wfold) {
  int t = threadIdx.x;        // t = h*16 + k
  int h = t >> 4, k = t & 15;
  float s = 0.f;
#pragma unroll
  for (int c = 0; c < 16; ++c)
    s += We[(h * 16 + c) * 16 + k] * att_e[h * 16 + c];
  Wfold[t] = s;
}

// ---------------- degree histogram (int atomics only) ----------------------
__global__ __launch_bounds__(256) void k_hist(const int* __restrict__ ei,
                                              int* __restrict__ cnt, int E) {
  int e = blockIdx.x * 256 + threadIdx.x;
  if (e < E) atomicAdd(&cnt[ei[E + e]], 1);
}

// ---------------- scans ----------------------------------------------------
__global__ __launch_bounds__(256) void k_scan1(const int* __restrict__ cnt,
                                               int* __restrict__ offs,
                                               int* __restrict__ bsum, int N) {
  __shared__ int s[256];
  int i = blockIdx.x * 256 + threadIdx.x;
  int v = (i < N) ? cnt[i] : 0;
  s[threadIdx.x] = v;
  __syncthreads();
  for (int off = 1; off < 256; off <<= 1) {
    int t = (threadIdx.x >= off) ? s[threadIdx.x - off] : 0;
    __syncthreads();
    s[threadIdx.x] += t;
    __syncthreads();
  }
  if (i < N) offs[i] = s[threadIdx.x] - v;
  if (threadIdx.x == 255) bsum[blockIdx.x] = s[255];
}

__global__ __launch_bounds__(256) void k_scan2(const int* __restrict__ bsum,
                                               int* __restrict__ boffs, int NB) {
  __shared__ int s[256];
  int v = (threadIdx.x < NB) ? bsum[threadIdx.x] : 0;
  s[threadIdx.x] = v;
  __syncthreads();
  for (int off = 1; off < 256; off <<= 1) {
    int t = (threadIdx.x >= off) ? s[threadIdx.x - off] : 0;
    __syncthreads();
    s[threadIdx.x] += t;
    __syncthreads();
  }
  if (threadIdx.x < NB) boffs[threadIdx.x] = s[threadIdx.x] - v;
}

__global__ __launch_bounds__(256) void k_scan3(int* __restrict__ offs,
                                               const int* __restrict__ boffs,
                                               int* __restrict__ cursor, int N) {
  int i = blockIdx.x * 256 + threadIdx.x;
  if (i < N) {
    int o = offs[i] + boffs[blockIdx.x];
    offs[i] = o;
    cursor[i] = o;
  }
}

// ------ MFMA edge GEMM: eout + alpha_e + exp + CSR scatter, all fused ------
__global__ __launch_bounds__(256) void k_edgemfma(const float* __restrict__ ea,
                                                  const float* __restrict__ We,
                                                  const float* __restrict__ Wfold,
                                                  const float* __restrict__ ebias,
                                                  const int* __restrict__ ei,
                                                  const float* __restrict__ al,
                                                  const float* __restrict__ ar,
                                                  int* __restrict__ cur,
                                                  float* __restrict__ eout,
                                                  int* __restrict__ ssrc,
                                                  float* __restrict__ sex, int E) {
  int tid = threadIdx.x;
  int lane = tid & 63;
  int col = lane & 15;       // n index within 16-wide tile
  int kg = lane >> 4;        // k-group (4 k's each)

  // B fragments, registers for the whole kernel
  bf16x4 bfr0, bfr1, bfr2, bfr3, bfold;
  bfr0 = pack4(*(const float4*)(We + ((size_t)(0 * 16 + col) * 16 + kg * 4)));
  bfr1 = pack4(*(const float4*)(We + ((size_t)(1 * 16 + col) * 16 + kg * 4)));
  bfr2 = pack4(*(const float4*)(We + ((size_t)(2 * 16 + col) * 16 + kg * 4)));
  bfr3 = pack4(*(const float4*)(We + ((size_t)(3 * 16 + col) * 16 + kg * 4)));
  {
    float4 w = make_float4(0.f, 0.f, 0.f, 0.f);
    if (col < 4) w = *(const float4*)(Wfold + ((size_t)col * 16 + kg * 4));
    bfold = pack4(w);
  }
  float bias = ebias[col];

  int ebase = blockIdx.x * 256 + (tid >> 6) * 64;
#pragma unroll
  for (int t = 0; t < 4; ++t) {
    int tb = ebase + t * 16;
    if (tb >= E) break;
    float4 av = *(const float4*)(ea + (size_t)(tb + col) * EIN + kg * 4);
    bf16x4 afr = pack4(av);
    f32x4 z = {0.f, 0.f, 0.f, 0.f};
    f32x4 d0 = mfma16(afr, bfr0, z);
    f32x4 d1 = mfma16(afr, bfr1, z);
    f32x4 d2 = mfma16(afr, bfr2, z);
    f32x4 d3 = mfma16(afr, bfr3, z);
    f32x4 d4 = mfma16(afr, bfold, z);

    // eout: lane holds e[edge = kg*4+reg][col] for head nt in d{nt}[reg]
#pragma unroll
    for (int reg = 0; reg < 4; ++reg) {
      float m = fmaxf(fmaxf(d0[reg], d1[reg]), fmaxf(d2[reg], d3[reg]));
      eout[(size_t)(tb + kg * 4 + reg) * EOUT + col] = fmaxf(m + bias, 0.f);
    }

    // alpha_e: d4 lane(l') holds alpha[h=l'&15][edge=4*(l'>>4)+reg] (h<4)
    // target: lane l handles (edge = l>>2, h = l&3)
    int srcl = (lane & 48) | (lane & 3);
    float t0 = __shfl(d4[0], srcl);
    float t1 = __shfl(d4[1], srcl);
    float t2 = __shfl(d4[2], srcl);
    float t3 = __shfl(d4[3], srcl);
    int q = (lane >> 2) & 3;
    float alpha = (q == 0) ? t0 : (q == 1) ? t1 : (q == 2) ? t2 : t3;

    int g = tb + (lane >> 2);
    int h = lane & 3;
    int sN = ei[g];
    int dN = ei[E + g];
    float lg = al[(size_t)sN * H + h] + ar[(size_t)dN * H + h] + alpha;
    lg = (lg >= 0.f) ? lg : NEG_SLOPE * lg;
    float ev = __expf(lg);

    int p = 0;
    if (h == 0) p = atomicAdd(&cur[dN], 1);
    p = __shfl(p, lane & ~3);
    sex[(size_t)p * H + h] = ev;
    if (h == 0) ssrc[p] = sN;
  }
}

// ------- aggregation: wave per node, 8B gather/edge, inline denominator ----
__global__ __launch_bounds__(256) void k_agg(const ushortT* __restrict__ xlb,
                                             const int* __restrict__ ssrc,
                                             const float* __restrict__ sex,
                                             const int* __restrict__ offs,
                                             const int* __restrict__ cnt,
                                             const float* __restrict__ nbias,
                                             float* __restrict__ out, int N) {
  int wv = (blockIdx.x * 256 + threadIdx.x) >> 6;
  int lane = threadIdx.x & 63;
  if (wv >= N) return;
  int deg = cnt[wv];
  int start = offs[wv];
  float acc0 = 0.f, acc1 = 0.f, acc2 = 0.f, acc3 = 0.f;
  float s0 = 0.f, s1 = 0.f, s2 = 0.f, s3 = 0.f;

  int i = 0;
  for (; i + 1 < deg; i += 2) {
    int sA = ssrc[start + i];
    int sB = ssrc[start + i + 1];
    float4 e0 = *(const float4*)(sex + (size_t)(start + i) * H);
    float4 e1 = *(const float4*)(sex + (size_t)(start + i + 1) * H);
    uint2 uA = *(const uint2*)(xlb + (size_t)sA * 256 + lane * 4);
    uint2 uB = *(const uint2*)(xlb + (size_t)sB * 256 + lane * 4);
    float xA0 = __uint_as_float(uA.x << 16);
    float xA1 = __uint_as_float(uA.x & 0xFFFF0000u);
    float xA2 = __uint_as_float(uA.y << 16);
    float xA3 = __uint_as_float(uA.y & 0xFFFF0000u);
    float xB0 = __uint_as_float(uB.x << 16);
    float xB1 = __uint_as_float(uB.x & 0xFFFF0000u);
    float xB2 = __uint_as_float(uB.y << 16);
    float xB3 = __uint_as_float(uB.y & 0xFFFF0000u);
    acc0 += e0.x * xA0 + e1.x * xB0;
    acc1 += e0.y * xA1 + e1.y * xB1;
    acc2 += e0.z * xA2 + e1.z * xB2;
    acc3 += e0.w * xA3 + e1.w * xB3;
    s0 += e0.x + e1.x;
    s1 += e0.y + e1.y;
    s2 += e0.z + e1.z;
    s3 += e0.w + e1.w;
  }
  if (i < deg) {
    int sA = ssrc[start + i];
    float4 e0 = *(const float4*)(sex + (size_t)(start + i) * H);
    uint2 uA = *(const uint2*)(xlb + (size_t)sA * 256 + lane * 4);
    acc0 += e0.x * __uint_as_float(uA.x << 16);
    acc1 += e0.y * __uint_as_float(uA.x & 0xFFFF0000u);
    acc2 += e0.z * __uint_as_float(uA.y << 16);
    acc3 += e0.w * __uint_as_float(uA.y & 0xFFFF0000u);
    s0 += e0.x; s1 += e0.y; s2 += e0.z; s3 += e0.w;
  }
  float best = acc0 / (s0 + 1e-16f);
  best = fmaxf(best, acc1 / (s1 + 1e-16f));
  best = fmaxf(best, acc2 / (s2 + 1e-16f));
  best = fmaxf(best, acc3 / (s3 + 1e-16f));
  out[(size_t)wv * DOUT + lane] = fmaxf(best + nbias[lane], 0.f);
}

// ---------------- launcher -------------------------------------------------
extern "C" void kernel_launch(void* const* d_in, const int* in_sizes, int n_in,
                              void* d_out, int out_size, void* d_ws, size_t ws_size,
                              hipStream_t stream) {
  const float* x     = (const float*)d_in[0];
  const float* ea    = (const float*)d_in[1];
  const int*   ei    = (const int*)d_in[2];
  const float* Wl    = (const float*)d_in[3];
  const float* We    = (const float*)d_in[4];
  const float* att_l = (const float*)d_in[5];
  const float* att_r = (const float*)d_in[6];
  const float* att_e = (const float*)d_in[7];
  const float* nbias = (const float*)d_in[8];
  const float* ebias = (const float*)d_in[9];

  int N = in_sizes[0] / DIN;
  int E = in_sizes[1] / EIN;

  float* out  = (float*)d_out;
  float* eout = (float*)d_out + (size_t)N * DOUT;

  char* w = (char*)d_ws;
  auto alloc = [&](size_t bytes) -> void* {
    void* p = (void*)w;
    w += (bytes + 255) & ~(size_t)255;
    return p;
  };
  ushortT* xlb = (ushortT*)alloc((size_t)N * 256 * 2);
  float* al    = (float*)alloc((size_t)N * H * 4);
  float* ar    = (float*)alloc((size_t)N * H * 4);
  float* Wfold = (float*)alloc(64 * 4);
  int* cnt     = (int*)alloc((size_t)N * 4);
  int* offs    = (int*)alloc((size_t)N * 4);
  int* cur     = (int*)alloc((size_t)N * 4);
  int* bsum    = (int*)alloc(256 * 4);
  int* boffs   = (int*)alloc(256 * 4);
  int* ssrc    = (int*)alloc((size_t)E * 4);
  float* sex   = (float*)alloc((size_t)E * H * 4);

  hipMemsetAsync(cnt, 0, (size_t)N * 4, stream);

  dim3 gnp((N + 63) / 64, H);
  k_nodeproj<<<gnp, 256, 0, stream>>>(x, Wl, att_l, att_r, xlb, al, ar, N);
  k_setup<<<1, 64, 0, stream>>>(We, att_e, Wfold);
  k_hist<<<(E + 255) / 256, 256, 0, stream>>>(ei, cnt, E);
  int NB = (N + 255) / 256;
  k_scan1<<<NB, 256, 0, stream>>>(cnt, offs, bsum, N);
  k_scan2<<<1, 256, 0, stream>>>(bsum, boffs, NB);
  k_scan3<<<NB, 256, 0, stream>>>(offs, boffs, cur, N);
  k_edgemfma<<<(E + 255) / 256, 256, 0, stream>>>(ea, We, Wfold, ebias, ei, al, ar,
                                                  cur, eout, ssrc, sex, E);
  k_agg<<<(N * 64 + 255) / 256, 256, 0, stream>>>(xlb, ssrc, sex, offs, cnt,
                                                  nbias, out, N);
}

// Round 5
// 210.056 us; speedup vs baseline: 1.9678x; 1.2294x over previous
//
#include <hip/hip_runtime.h>

#define H 4
#define DIN 128
#define DOUT 64
#define EIN 16
#define EOUT 16
#define NEG_SLOPE 0.2f

typedef unsigned short ushortT;
typedef __attribute__((ext_vector_type(4))) short bf16x4;
typedef __attribute__((ext_vector_type(8))) short bf16x8;
typedef __attribute__((ext_vector_type(4))) float f32x4;

static __device__ __forceinline__ ushortT f2bf(float f) {
  unsigned x = __float_as_uint(f);
  unsigned r = (x + 0x7FFFu + ((x >> 16) & 1u)) >> 16;   // RNE
  return (ushortT)r;
}

static __device__ __forceinline__ bf16x4 pack4(float4 v) {
  bf16x4 r;
  r[0] = (short)f2bf(v.x);
  r[1] = (short)f2bf(v.y);
  r[2] = (short)f2bf(v.z);
  r[3] = (short)f2bf(v.w);
  return r;
}

#if __has_builtin(__builtin_amdgcn_mfma_f32_16x16x16bf16_1k)
static __device__ __forceinline__ f32x4 mfma16(bf16x4 a, bf16x4 b, f32x4 c) {
  return __builtin_amdgcn_mfma_f32_16x16x16bf16_1k(a, b, c, 0, 0, 0);
}
#else
static __device__ __forceinline__ f32x4 mfma16(bf16x4 a, bf16x4 b, f32x4 c) {
  f32x4 d;
  asm volatile("v_mfma_f32_16x16x16_bf16 %0, %1, %2, %3"
               : "=v"(d) : "v"(a), "v"(b), "v"(c));
  return d;
}
#endif

static __device__ __forceinline__ f32x4 mfma32(bf16x8 a, bf16x8 b, f32x4 c) {
  return __builtin_amdgcn_mfma_f32_16x16x32_bf16(a, b, c, 0, 0, 0);
}

// ------------- MFMA node projection + fused alpha_l/alpha_r ----------------
// block = 64 rows x 256 cols; wave w = head w (64 cols). 16x16x32 bf16 MFMA.
// xlb[N][64 chan][4 heads] bf16 ; al/ar[N][H]
__global__ __launch_bounds__(256) void k_nodeproj(const float* __restrict__ x,
                                                  const float* __restrict__ Wl,
                                                  const float* __restrict__ att_l,
                                                  const float* __restrict__ att_r,
                                                  ushortT* __restrict__ xlb,
                                                  float* __restrict__ al,
                                                  float* __restrict__ ar, int N) {
  // A in fragment-native layout: [kt][kg][row swizzled][8 bf16] = 16 KB
  __shared__ ushortT Alds[4][4][64][8];
  int tid = threadIdx.x;
  int w = tid >> 6;          // wave = head
  int lane = tid & 63;
  int c16 = lane & 15;       // A-row / B-col within 16-tile
  int kg = lane >> 4;        // k-group
  int m0 = blockIdx.x * 64;

  // ---- stage A: fp32 -> bf16, fragment layout, XOR row-swizzle ----
  for (int f = tid; f < 64 * 32; f += 256) {
    int r = f >> 5, m = f & 31;          // m indexes float4 along K
    int gr = m0 + r;
    float4 v = make_float4(0.f, 0.f, 0.f, 0.f);
    if (gr < N) v = *(const float4*)(x + (size_t)gr * DIN + m * 4);
    int kt = m >> 3, half = (m >> 2) & 1, kq = m & 3;
    int rs = r ^ kq ^ ((kt & 1) << 2);
    *(bf16x4*)&Alds[kt][kq][rs][half * 4] = pack4(v);
  }

  // ---- B fragments in registers: cols w*64 + ct*16 + c16, K=128 ----
  bf16x8 bfr[4][4];
  const float* wbase = Wl + (size_t)(w * 64 + c16) * DIN;
#pragma unroll
  for (int ct = 0; ct < 4; ++ct) {
#pragma unroll
    for (int kt = 0; kt < 4; ++kt) {
      const float* wp = wbase + (size_t)ct * 16 * DIN + kt * 32 + kg * 4;
      float4 lo = *(const float4*)(wp);
      float4 hi = *(const float4*)(wp + 16);
      bf16x8 bb;
      bb[0] = (short)f2bf(lo.x); bb[1] = (short)f2bf(lo.y);
      bb[2] = (short)f2bf(lo.z); bb[3] = (short)f2bf(lo.w);
      bb[4] = (short)f2bf(hi.x); bb[5] = (short)f2bf(hi.y);
      bb[6] = (short)f2bf(hi.z); bb[7] = (short)f2bf(hi.w);
      bfr[ct][kt] = bb;
    }
  }

  f32x4 acc[4][4];
#pragma unroll
  for (int rt = 0; rt < 4; ++rt)
#pragma unroll
    for (int ct = 0; ct < 4; ++ct) acc[rt][ct] = (f32x4){0.f, 0.f, 0.f, 0.f};

  __syncthreads();

#pragma unroll
  for (int kt = 0; kt < 4; ++kt) {
    bf16x8 afr[4];
#pragma unroll
    for (int rt = 0; rt < 4; ++rt) {
      int rs = (rt * 16 + c16) ^ kg ^ ((kt & 1) << 2);
      afr[rt] = *(const bf16x8*)&Alds[kt][kg][rs][0];
    }
#pragma unroll
    for (int rt = 0; rt < 4; ++rt)
#pragma unroll
      for (int ct = 0; ct < 4; ++ct)
        acc[rt][ct] = mfma32(afr[rt], bfr[ct][kt], acc[rt][ct]);
  }

  // ---- epilogue: alpha partials (shfl reduce over c16) + bf16 stores ----
  float attl[4], attr[4];
#pragma unroll
  for (int ct = 0; ct < 4; ++ct) {
    attl[ct] = att_l[w * 64 + ct * 16 + c16];
    attr[ct] = att_r[w * 64 + ct * 16 + c16];
  }

#pragma unroll
  for (int rt = 0; rt < 4; ++rt) {
#pragma unroll
    for (int reg = 0; reg < 4; ++reg) {
      int r = rt * 16 + kg * 4 + reg;   // C/D row = 4*kg + reg
      int gr = m0 + r;
      float pl = acc[rt][0][reg] * attl[0] + acc[rt][1][reg] * attl[1] +
                 acc[rt][2][reg] * attl[2] + acc[rt][3][reg] * attl[3];
      float pr = acc[rt][0][reg] * attr[0] + acc[rt][1][reg] * attr[1] +
                 acc[rt][2][reg] * attr[2] + acc[rt][3][reg] * attr[3];
#pragma unroll
      for (int off = 1; off < 16; off <<= 1) {
        pl += __shfl_xor(pl, off);
        pr += __shfl_xor(pr, off);
      }
      if (gr < N) {
        if (c16 == 0) {
          al[(size_t)gr * H + w] = pl;
          ar[(size_t)gr * H + w] = pr;
        }
#pragma unroll
        for (int ct = 0; ct < 4; ++ct)
          xlb[(size_t)gr * 256 + (ct * 16 + c16) * 4 + w] = f2bf(acc[rt][ct][reg]);
      }
    }
  }
}

// ---------------- Wfold[h][k] = sum_c We[h*16+c][k] * att_e[h*16+c] --------
__global__ __launch_bounds__(64) void k_setup(const float* __restrict__ We,
                                              const float* __restrict__ att_e,
                                              float* __restrict__ Wfold) {
  int t = threadIdx.x;        // t = h*16 + k
  int h = t >> 4, k = t & 15;
  float s = 0.f;
#pragma unroll
  for (int c = 0; c < 16; ++c)
    s += We[(h * 16 + c) * 16 + k] * att_e[h * 16 + c];
  Wfold[t] = s;
}

// ---------------- degree histogram (int atomics only) ----------------------
__global__ __launch_bounds__(256) void k_hist(const int* __restrict__ ei,
                                              int* __restrict__ cnt, int E) {
  int e = blockIdx.x * 256 + threadIdx.x;
  if (e < E) atomicAdd(&cnt[ei[E + e]], 1);
}

// ---------------- scans ----------------------------------------------------
__global__ __launch_bounds__(256) void k_scan1(const int* __restrict__ cnt,
                                               int* __restrict__ offs,
                                               int* __restrict__ bsum, int N) {
  __shared__ int s[256];
  int i = blockIdx.x * 256 + threadIdx.x;
  int v = (i < N) ? cnt[i] : 0;
  s[threadIdx.x] = v;
  __syncthreads();
  for (int off = 1; off < 256; off <<= 1) {
    int t = (threadIdx.x >= off) ? s[threadIdx.x - off] : 0;
    __syncthreads();
    s[threadIdx.x] += t;
    __syncthreads();
  }
  if (i < N) offs[i] = s[threadIdx.x] - v;
  if (threadIdx.x == 255) bsum[blockIdx.x] = s[255];
}

__global__ __launch_bounds__(256) void k_scan2(const int* __restrict__ bsum,
                                               int* __restrict__ boffs, int NB) {
  __shared__ int s[256];
  int v = (threadIdx.x < NB) ? bsum[threadIdx.x] : 0;
  s[threadIdx.x] = v;
  __syncthreads();
  for (int off = 1; off < 256; off <<= 1) {
    int t = (threadIdx.x >= off) ? s[threadIdx.x - off] : 0;
    __syncthreads();
    s[threadIdx.x] += t;
    __syncthreads();
  }
  if (threadIdx.x < NB) boffs[threadIdx.x] = s[threadIdx.x] - v;
}

__global__ __launch_bounds__(256) void k_scan3(int* __restrict__ offs,
                                               const int* __restrict__ boffs,
                                               int* __restrict__ cursor, int N) {
  int i = blockIdx.x * 256 + threadIdx.x;
  if (i < N) {
    int o = offs[i] + boffs[blockIdx.x];
    offs[i] = o;
    cursor[i] = o;
  }
}

// ------ MFMA edge GEMM: eout + alpha_e + exp + CSR scatter, all fused ------
__global__ __launch_bounds__(256) void k_edgemfma(const float* __restrict__ ea,
                                                  const float* __restrict__ We,
                                                  const float* __restrict__ Wfold,
                                                  const float* __restrict__ ebias,
                                                  const int* __restrict__ ei,
                                                  const float* __restrict__ al,
                                                  const float* __restrict__ ar,
                                                  int* __restrict__ cur,
                                                  float* __restrict__ eout,
                                                  int* __restrict__ ssrc,
                                                  float* __restrict__ sex, int E) {
  int tid = threadIdx.x;
  int lane = tid & 63;
  int col = lane & 15;       // n index within 16-wide tile
  int kg = lane >> 4;        // k-group (4 k's each)

  // B fragments, registers for the whole kernel
  bf16x4 bfr0, bfr1, bfr2, bfr3, bfold;
  bfr0 = pack4(*(const float4*)(We + ((size_t)(0 * 16 + col) * 16 + kg * 4)));
  bfr1 = pack4(*(const float4*)(We + ((size_t)(1 * 16 + col) * 16 + kg * 4)));
  bfr2 = pack4(*(const float4*)(We + ((size_t)(2 * 16 + col) * 16 + kg * 4)));
  bfr3 = pack4(*(const float4*)(We + ((size_t)(3 * 16 + col) * 16 + kg * 4)));
  {
    float4 w = make_float4(0.f, 0.f, 0.f, 0.f);
    if (col < 4) w = *(const float4*)(Wfold + ((size_t)col * 16 + kg * 4));
    bfold = pack4(w);
  }
  float bias = ebias[col];

  int ebase = blockIdx.x * 256 + (tid >> 6) * 64;
#pragma unroll
  for (int t = 0; t < 4; ++t) {
    int tb = ebase + t * 16;
    if (tb >= E) break;
    float4 av = *(const float4*)(ea + (size_t)(tb + col) * EIN + kg * 4);
    bf16x4 afr = pack4(av);
    f32x4 z = {0.f, 0.f, 0.f, 0.f};
    f32x4 d0 = mfma16(afr, bfr0, z);
    f32x4 d1 = mfma16(afr, bfr1, z);
    f32x4 d2 = mfma16(afr, bfr2, z);
    f32x4 d3 = mfma16(afr, bfr3, z);
    f32x4 d4 = mfma16(afr, bfold, z);

    // eout: lane holds e[edge = kg*4+reg][col] for head nt in d{nt}[reg]
#pragma unroll
    for (int reg = 0; reg < 4; ++reg) {
      float m = fmaxf(fmaxf(d0[reg], d1[reg]), fmaxf(d2[reg], d3[reg]));
      eout[(size_t)(tb + kg * 4 + reg) * EOUT + col] = fmaxf(m + bias, 0.f);
    }

    // alpha_e: d4 lane(l') holds alpha[h=l'&15][edge=4*(l'>>4)+reg] (h<4)
    int srcl = (lane & 48) | (lane & 3);
    float t0 = __shfl(d4[0], srcl);
    float t1 = __shfl(d4[1], srcl);
    float t2 = __shfl(d4[2], srcl);
    float t3 = __shfl(d4[3], srcl);
    int q = (lane >> 2) & 3;
    float alpha = (q == 0) ? t0 : (q == 1) ? t1 : (q == 2) ? t2 : t3;

    int g = tb + (lane >> 2);
    int h = lane & 3;
    int sN = ei[g];
    int dN = ei[E + g];
    float lg = al[(size_t)sN * H + h] + ar[(size_t)dN * H + h] + alpha;
    lg = (lg >= 0.f) ? lg : NEG_SLOPE * lg;
    float ev = __expf(lg);

    int p = 0;
    if (h == 0) p = atomicAdd(&cur[dN], 1);
    p = __shfl(p, lane & ~3);
    sex[(size_t)p * H + h] = ev;
    if (h == 0) ssrc[p] = sN;
  }
}

// ------- aggregation: wave per node, 8B gather/edge, inline denominator ----
__global__ __launch_bounds__(256) void k_agg(const ushortT* __restrict__ xlb,
                                             const int* __restrict__ ssrc,
                                             const float* __restrict__ sex,
                                             const int* __restrict__ offs,
                                             const int* __restrict__ cnt,
                                             const float* __restrict__ nbias,
                                             float* __restrict__ out, int N) {
  int wv = (blockIdx.x * 256 + threadIdx.x) >> 6;
  int lane = threadIdx.x & 63;
  if (wv >= N) return;
  int deg = cnt[wv];
  int start = offs[wv];
  float acc0 = 0.f, acc1 = 0.f, acc2 = 0.f, acc3 = 0.f;
  float s0 = 0.f, s1 = 0.f, s2 = 0.f, s3 = 0.f;

  int i = 0;
  for (; i + 1 < deg; i += 2) {
    int sA = ssrc[start + i];
    int sB = ssrc[start + i + 1];
    float4 e0 = *(const float4*)(sex + (size_t)(start + i) * H);
    float4 e1 = *(const float4*)(sex + (size_t)(start + i + 1) * H);
    uint2 uA = *(const uint2*)(xlb + (size_t)sA * 256 + lane * 4);
    uint2 uB = *(const uint2*)(xlb + (size_t)sB * 256 + lane * 4);
    float xA0 = __uint_as_float(uA.x << 16);
    float xA1 = __uint_as_float(uA.x & 0xFFFF0000u);
    float xA2 = __uint_as_float(uA.y << 16);
    float xA3 = __uint_as_float(uA.y & 0xFFFF0000u);
    float xB0 = __uint_as_float(uB.x << 16);
    float xB1 = __uint_as_float(uB.x & 0xFFFF0000u);
    float xB2 = __uint_as_float(uB.y << 16);
    float xB3 = __uint_as_float(uB.y & 0xFFFF0000u);
    acc0 += e0.x * xA0 + e1.x * xB0;
    acc1 += e0.y * xA1 + e1.y * xB1;
    acc2 += e0.z * xA2 + e1.z * xB2;
    acc3 += e0.w * xA3 + e1.w * xB3;
    s0 += e0.x + e1.x;
    s1 += e0.y + e1.y;
    s2 += e0.z + e1.z;
    s3 += e0.w + e1.w;
  }
  if (i < deg) {
    int sA = ssrc[start + i];
    float4 e0 = *(const float4*)(sex + (size_t)(start + i) * H);
    uint2 uA = *(const uint2*)(xlb + (size_t)sA * 256 + lane * 4);
    acc0 += e0.x * __uint_as_float(uA.x << 16);
    acc1 += e0.y * __uint_as_float(uA.x & 0xFFFF0000u);
    acc2 += e0.z * __uint_as_float(uA.y << 16);
    acc3 += e0.w * __uint_as_float(uA.y & 0xFFFF0000u);
    s0 += e0.x; s1 += e0.y; s2 += e0.z; s3 += e0.w;
  }
  float best = acc0 / (s0 + 1e-16f);
  best = fmaxf(best, acc1 / (s1 + 1e-16f));
  best = fmaxf(best, acc2 / (s2 + 1e-16f));
  best = fmaxf(best, acc3 / (s3 + 1e-16f));
  out[(size_t)wv * DOUT + lane] = fmaxf(best + nbias[lane], 0.f);
}

// ---------------- launcher -------------------------------------------------
extern "C" void kernel_launch(void* const* d_in, const int* in_sizes, int n_in,
                              void* d_out, int out_size, void* d_ws, size_t ws_size,
                              hipStream_t stream) {
  const float* x     = (const float*)d_in[0];
  const float* ea    = (const float*)d_in[1];
  const int*   ei    = (const int*)d_in[2];
  const float* Wl    = (const float*)d_in[3];
  const float* We    = (const float*)d_in[4];
  const float* att_l = (const float*)d_in[5];
  const float* att_r = (const float*)d_in[6];
  const float* att_e = (const float*)d_in[7];
  const float* nbias = (const float*)d_in[8];
  const float* ebias = (const float*)d_in[9];

  int N = in_sizes[0] / DIN;
  int E = in_sizes[1] / EIN;

  float* out  = (float*)d_out;
  float* eout = (float*)d_out + (size_t)N * DOUT;

  char* w = (char*)d_ws;
  auto alloc = [&](size_t bytes) -> void* {
    void* p = (void*)w;
    w += (bytes + 255) & ~(size_t)255;
    return p;
  };
  ushortT* xlb = (ushortT*)alloc((size_t)N * 256 * 2);
  float* al    = (float*)alloc((size_t)N * H * 4);
  float* ar    = (float*)alloc((size_t)N * H * 4);
  float* Wfold = (float*)alloc(64 * 4);
  int* cnt     = (int*)alloc((size_t)N * 4);
  int* offs    = (int*)alloc((size_t)N * 4);
  int* cur     = (int*)alloc((size_t)N * 4);
  int* bsum    = (int*)alloc(256 * 4);
  int* boffs   = (int*)alloc(256 * 4);
  int* ssrc    = (int*)alloc((size_t)E * 4);
  float* sex   = (float*)alloc((size_t)E * H * 4);

  hipMemsetAsync(cnt, 0, (size_t)N * 4, stream);

  k_nodeproj<<<(N + 63) / 64, 256, 0, stream>>>(x, Wl, att_l, att_r, xlb, al, ar, N);
  k_setup<<<1, 64, 0, stream>>>(We, att_e, Wfold);
  k_hist<<<(E + 255) / 256, 256, 0, stream>>>(ei, cnt, E);
  int NB = (N + 255) / 256;
  k_scan1<<<NB, 256, 0, stream>>>(cnt, offs, bsum, N);
  k_scan2<<<1, 256, 0, stream>>>(bsum, boffs, NB);
  k_scan3<<<NB, 256, 0, stream>>>(offs, boffs, cur, N);
  k_edgemfma<<<(E + 255) / 256, 256, 0, stream>>>(ea, We, Wfold, ebias, ei, al, ar,
                                                  cur, eout, ssrc, sex, E);
  k_agg<<<(N * 64 + 255) / 256, 256, 0, stream>>>(xlb, ssrc, sex, offs, cnt,
                                                  nbias, out, N);
}

// Round 6
// 198.168 us; speedup vs baseline: 2.0859x; 1.0600x over previous
//
#include <hip/hip_runtime.h>

#define H 4
#define DIN 128
#define DOUT 64
#define EIN 16
#define EOUT 16
#define NEG_SLOPE 0.2f

typedef unsigned short ushortT;
typedef __attribute__((ext_vector_type(4))) short bf16x4;
typedef __attribute__((ext_vector_type(8))) short bf16x8;
typedef __attribute__((ext_vector_type(4))) float f32x4;

static __device__ __forceinline__ ushortT f2bf(float f) {
  unsigned x = __float_as_uint(f);
  unsigned r = (x + 0x7FFFu + ((x >> 16) & 1u)) >> 16;   // RNE
  return (ushortT)r;
}

static __device__ __forceinline__ bf16x4 pack4(float4 v) {
  bf16x4 r;
  r[0] = (short)f2bf(v.x);
  r[1] = (short)f2bf(v.y);
  r[2] = (short)f2bf(v.z);
  r[3] = (short)f2bf(v.w);
  return r;
}

#if __has_builtin(__builtin_amdgcn_mfma_f32_16x16x16bf16_1k)
static __device__ __forceinline__ f32x4 mfma16(bf16x4 a, bf16x4 b, f32x4 c) {
  return __builtin_amdgcn_mfma_f32_16x16x16bf16_1k(a, b, c, 0, 0, 0);
}
#else
static __device__ __forceinline__ f32x4 mfma16(bf16x4 a, bf16x4 b, f32x4 c) {
  f32x4 d;
  asm volatile("v_mfma_f32_16x16x16_bf16 %0, %1, %2, %3"
               : "=v"(d) : "v"(a), "v"(b), "v"(c));
  return d;
}
#endif

static __device__ __forceinline__ f32x4 mfma32(bf16x8 a, bf16x8 b, f32x4 c) {
  return __builtin_amdgcn_mfma_f32_16x16x32_bf16(a, b, c, 0, 0, 0);
}

// ------------- MFMA node projection + fused alpha_l/alpha_r + hist ---------
// block = 64 rows x 256 cols; wave w = head w (64 cols). 16x16x32 bf16 MFMA.
// xlb[N][64 chan][4 heads] bf16 ; al/ar[N][H] ; cnt histogram (grid-stride)
__global__ __launch_bounds__(256) void k_nodeproj(const float* __restrict__ x,
                                                  const float* __restrict__ Wl,
                                                  const float* __restrict__ att_l,
                                                  const float* __restrict__ att_r,
                                                  const int* __restrict__ eidst,
                                                  int* __restrict__ cnt,
                                                  ushortT* __restrict__ xlb,
                                                  float* __restrict__ al,
                                                  float* __restrict__ ar,
                                                  int N, int E) {
  // A in fragment-native layout: [kt][kg][row swizzled][8 bf16] = 16 KB
  __shared__ ushortT Alds[4][4][64][8];
  int tid = threadIdx.x;
  int w = tid >> 6;          // wave = head
  int lane = tid & 63;
  int c16 = lane & 15;       // A-row / B-col within 16-tile
  int kg = lane >> 4;        // k-group
  int m0 = blockIdx.x * 64;

  // ---- stage A: fp32 -> bf16, fragment layout, XOR row-swizzle ----
  for (int f = tid; f < 64 * 32; f += 256) {
    int r = f >> 5, m = f & 31;          // m indexes float4 along K
    int gr = m0 + r;
    float4 v = make_float4(0.f, 0.f, 0.f, 0.f);
    if (gr < N) v = *(const float4*)(x + (size_t)gr * DIN + m * 4);
    int kt = m >> 3, half = (m >> 2) & 1, kq = m & 3;
    int rs = r ^ kq ^ ((kt & 1) << 2);
    *(bf16x4*)&Alds[kt][kq][rs][half * 4] = pack4(v);
  }

  // ---- B fragments in registers: cols w*64 + ct*16 + c16, K=128 ----
  bf16x8 bfr[4][4];
  const float* wbase = Wl + (size_t)(w * 64 + c16) * DIN;
#pragma unroll
  for (int ct = 0; ct < 4; ++ct) {
#pragma unroll
    for (int kt = 0; kt < 4; ++kt) {
      const float* wp = wbase + (size_t)ct * 16 * DIN + kt * 32 + kg * 4;
      float4 lo = *(const float4*)(wp);
      float4 hi = *(const float4*)(wp + 16);
      bf16x8 bb;
      bb[0] = (short)f2bf(lo.x); bb[1] = (short)f2bf(lo.y);
      bb[2] = (short)f2bf(lo.z); bb[3] = (short)f2bf(lo.w);
      bb[4] = (short)f2bf(hi.x); bb[5] = (short)f2bf(hi.y);
      bb[6] = (short)f2bf(hi.z); bb[7] = (short)f2bf(hi.w);
      bfr[ct][kt] = bb;
    }
  }

  f32x4 acc[4][4];
#pragma unroll
  for (int rt = 0; rt < 4; ++rt)
#pragma unroll
    for (int ct = 0; ct < 4; ++ct) acc[rt][ct] = (f32x4){0.f, 0.f, 0.f, 0.f};

  __syncthreads();

#pragma unroll
  for (int kt = 0; kt < 4; ++kt) {
    bf16x8 afr[4];
#pragma unroll
    for (int rt = 0; rt < 4; ++rt) {
      int rs = (rt * 16 + c16) ^ kg ^ ((kt & 1) << 2);
      afr[rt] = *(const bf16x8*)&Alds[kt][kg][rs][0];
    }
#pragma unroll
    for (int rt = 0; rt < 4; ++rt)
#pragma unroll
      for (int ct = 0; ct < 4; ++ct)
        acc[rt][ct] = mfma32(afr[rt], bfr[ct][kt], acc[rt][ct]);
  }

  // ---- epilogue: alpha partials (shfl reduce over c16) + bf16 stores ----
  float attl[4], attr[4];
#pragma unroll
  for (int ct = 0; ct < 4; ++ct) {
    attl[ct] = att_l[w * 64 + ct * 16 + c16];
    attr[ct] = att_r[w * 64 + ct * 16 + c16];
  }

#pragma unroll
  for (int rt = 0; rt < 4; ++rt) {
#pragma unroll
    for (int reg = 0; reg < 4; ++reg) {
      int r = rt * 16 + kg * 4 + reg;   // C/D row = 4*kg + reg
      int gr = m0 + r;
      float pl = acc[rt][0][reg] * attl[0] + acc[rt][1][reg] * attl[1] +
                 acc[rt][2][reg] * attl[2] + acc[rt][3][reg] * attl[3];
      float pr = acc[rt][0][reg] * attr[0] + acc[rt][1][reg] * attr[1] +
                 acc[rt][2][reg] * attr[2] + acc[rt][3][reg] * attr[3];
#pragma unroll
      for (int off = 1; off < 16; off <<= 1) {
        pl += __shfl_xor(pl, off);
        pr += __shfl_xor(pr, off);
      }
      if (gr < N) {
        if (c16 == 0) {
          al[(size_t)gr * H + w] = pl;
          ar[(size_t)gr * H + w] = pr;
        }
#pragma unroll
        for (int ct = 0; ct < 4; ++ct)
          xlb[(size_t)gr * 256 + (ct * 16 + c16) * 4 + w] = f2bf(acc[rt][ct][reg]);
      }
    }
  }

  // ---- fused degree histogram (grid-stride over edges) ----
  int total = gridDim.x * 256;
  for (int e = blockIdx.x * 256 + tid; e < E; e += total)
    atomicAdd(&cnt[eidst[e]], 1);
}

// ---------------- scans ----------------------------------------------------
__global__ __launch_bounds__(256) void k_scan1(const int* __restrict__ cnt,
                                               int* __restrict__ offs,
                                               int* __restrict__ bsum, int N) {
  __shared__ int s[256];
  int i = blockIdx.x * 256 + threadIdx.x;
  int v = (i < N) ? cnt[i] : 0;
  s[threadIdx.x] = v;
  __syncthreads();
  for (int off = 1; off < 256; off <<= 1) {
    int t = (threadIdx.x >= off) ? s[threadIdx.x - off] : 0;
    __syncthreads();
    s[threadIdx.x] += t;
    __syncthreads();
  }
  if (i < N) offs[i] = s[threadIdx.x] - v;
  if (threadIdx.x == 255) bsum[blockIdx.x] = s[255];
}

__global__ __launch_bounds__(256) void k_scan2(const int* __restrict__ bsum,
                                               int* __restrict__ boffs, int NB) {
  __shared__ int s[256];
  int v = (threadIdx.x < NB) ? bsum[threadIdx.x] : 0;
  s[threadIdx.x] = v;
  __syncthreads();
  for (int off = 1; off < 256; off <<= 1) {
    int t = (threadIdx.x >= off) ? s[threadIdx.x - off] : 0;
    __syncthreads();
    s[threadIdx.x] += t;
    __syncthreads();
  }
  if (threadIdx.x < NB) boffs[threadIdx.x] = s[threadIdx.x] - v;
}

__global__ __launch_bounds__(256) void k_scan3(int* __restrict__ offs,
                                               const int* __restrict__ boffs,
                                               int* __restrict__ cursor, int N) {
  int i = blockIdx.x * 256 + threadIdx.x;
  if (i < N) {
    int o = offs[i] + boffs[blockIdx.x];
    offs[i] = o;
    cursor[i] = o;
  }
}

// ------ MFMA edge GEMM: eout + alpha_e + exp + CSR scatter, all fused ------
// Phase 1: 4 MFMA tiles (64 edges/wave), alpha_e -> LDS.
// Phase 2: lane l owns edge ebase+l -> 64-wide gather/exp/atomic/scatter.
__global__ __launch_bounds__(256) void k_edgemfma(const float* __restrict__ ea,
                                                  const float* __restrict__ We,
                                                  const float* __restrict__ att_e,
                                                  const float* __restrict__ ebias,
                                                  const int* __restrict__ ei,
                                                  const float* __restrict__ al,
                                                  const float* __restrict__ ar,
                                                  int* __restrict__ cur,
                                                  float* __restrict__ eout,
                                                  int* __restrict__ ssrc,
                                                  float* __restrict__ sex, int E) {
  __shared__ float alds[4][4][64];   // [wave][head][local edge]
  int tid = threadIdx.x;
  int w = tid >> 6;
  int lane = tid & 63;
  int col = lane & 15;       // n index within 16-wide tile
  int kg = lane >> 4;        // k-group (4 k's each)

  // B fragments, registers for the whole kernel
  bf16x4 bfr0, bfr1, bfr2, bfr3, bfold;
  bfr0 = pack4(*(const float4*)(We + ((size_t)(0 * 16 + col) * 16 + kg * 4)));
  bfr1 = pack4(*(const float4*)(We + ((size_t)(1 * 16 + col) * 16 + kg * 4)));
  bfr2 = pack4(*(const float4*)(We + ((size_t)(2 * 16 + col) * 16 + kg * 4)));
  bfr3 = pack4(*(const float4*)(We + ((size_t)(3 * 16 + col) * 16 + kg * 4)));
  {
    // inline Wfold: wf[j] = sum_c We[(col*16+c)][kg*4+j] * att_e[col*16+c]
    float wf0 = 0.f, wf1 = 0.f, wf2 = 0.f, wf3 = 0.f;
    if (col < 4) {
#pragma unroll
      for (int c = 0; c < 16; ++c) {
        float av = att_e[col * 16 + c];
        float4 wv = *(const float4*)(We + (size_t)(col * 16 + c) * 16 + kg * 4);
        wf0 += wv.x * av; wf1 += wv.y * av;
        wf2 += wv.z * av; wf3 += wv.w * av;
      }
    }
    bfold = pack4(make_float4(wf0, wf1, wf2, wf3));
  }
  float bias = ebias[col];

  int ebase = blockIdx.x * 256 + w * 64;

  // ---- phase 1: MFMA tiles ----
#pragma unroll
  for (int t = 0; t < 4; ++t) {
    int tb = ebase + t * 16;
    if (tb >= E) break;
    float4 av = *(const float4*)(ea + (size_t)(tb + col) * EIN + kg * 4);
    bf16x4 afr = pack4(av);
    f32x4 z = {0.f, 0.f, 0.f, 0.f};
    f32x4 d0 = mfma16(afr, bfr0, z);
    f32x4 d1 = mfma16(afr, bfr1, z);
    f32x4 d2 = mfma16(afr, bfr2, z);
    f32x4 d3 = mfma16(afr, bfr3, z);
    f32x4 d4 = mfma16(afr, bfold, z);

    // eout: lane holds e[edge = kg*4+reg][col] for head nt in d{nt}[reg]
#pragma unroll
    for (int reg = 0; reg < 4; ++reg) {
      float m = fmaxf(fmaxf(d0[reg], d1[reg]), fmaxf(d2[reg], d3[reg]));
      eout[(size_t)(tb + kg * 4 + reg) * EOUT + col] = fmaxf(m + bias, 0.f);
    }

    // alpha_e -> LDS: d4[reg] = alpha[h=col][edge = t*16 + kg*4 + reg]
    if (col < 4) {
#pragma unroll
      for (int reg = 0; reg < 4; ++reg)
        alds[w][col][t * 16 + kg * 4 + reg] = d4[reg];
    }
  }

  // ---- phase 2: 64-wide scatter (same-wave LDS, no barrier needed) ----
  int g = ebase + lane;
  if (g < E) {
    int sN = ei[g];
    int dN = ei[E + g];
    float4 a4 = *(const float4*)(al + (size_t)sN * H);
    float4 r4 = *(const float4*)(ar + (size_t)dN * H);
    float lg0 = a4.x + r4.x + alds[w][0][lane];
    float lg1 = a4.y + r4.y + alds[w][1][lane];
    float lg2 = a4.z + r4.z + alds[w][2][lane];
    float lg3 = a4.w + r4.w + alds[w][3][lane];
    lg0 = (lg0 >= 0.f) ? lg0 : NEG_SLOPE * lg0;
    lg1 = (lg1 >= 0.f) ? lg1 : NEG_SLOPE * lg1;
    lg2 = (lg2 >= 0.f) ? lg2 : NEG_SLOPE * lg2;
    lg3 = (lg3 >= 0.f) ? lg3 : NEG_SLOPE * lg3;
    int p = atomicAdd(&cur[dN], 1);
    float4 ev = make_float4(__expf(lg0), __expf(lg1), __expf(lg2), __expf(lg3));
    *(float4*)(sex + (size_t)p * H) = ev;
    ssrc[p] = sN;
  }
}

// ------- aggregation: wave per node, 8B gather/edge, 4-wide unroll ---------
__global__ __launch_bounds__(256) void k_agg(const ushortT* __restrict__ xlb,
                                             const int* __restrict__ ssrc,
                                             const float* __restrict__ sex,
                                             const int* __restrict__ offs,
                                             const int* __restrict__ cnt,
                                             const float* __restrict__ nbias,
                                             float* __restrict__ out, int N) {
  int wv = (blockIdx.x * 256 + threadIdx.x) >> 6;
  int lane = threadIdx.x & 63;
  if (wv >= N) return;
  int deg = cnt[wv];
  int start = offs[wv];
  float acc0 = 0.f, acc1 = 0.f, acc2 = 0.f, acc3 = 0.f;
  float s0 = 0.f, s1 = 0.f, s2 = 0.f, s3 = 0.f;

  int i = 0;
  for (; i + 3 < deg; i += 4) {
    int sA = ssrc[start + i];
    int sB = ssrc[start + i + 1];
    int sC = ssrc[start + i + 2];
    int sD = ssrc[start + i + 3];
    float4 e0 = *(const float4*)(sex + (size_t)(start + i) * H);
    float4 e1 = *(const float4*)(sex + (size_t)(start + i + 1) * H);
    float4 e2 = *(const float4*)(sex + (size_t)(start + i + 2) * H);
    float4 e3 = *(const float4*)(sex + (size_t)(start + i + 3) * H);
    uint2 uA = *(const uint2*)(xlb + (size_t)sA * 256 + lane * 4);
    uint2 uB = *(const uint2*)(xlb + (size_t)sB * 256 + lane * 4);
    uint2 uC = *(const uint2*)(xlb + (size_t)sC * 256 + lane * 4);
    uint2 uD = *(const uint2*)(xlb + (size_t)sD * 256 + lane * 4);
    acc0 += e0.x * __uint_as_float(uA.x << 16) + e1.x * __uint_as_float(uB.x << 16) +
            e2.x * __uint_as_float(uC.x << 16) + e3.x * __uint_as_float(uD.x << 16);
    acc1 += e0.y * __uint_as_float(uA.x & 0xFFFF0000u) + e1.y * __uint_as_float(uB.x & 0xFFFF0000u) +
            e2.y * __uint_as_float(uC.x & 0xFFFF0000u) + e3.y * __uint_as_float(uD.x & 0xFFFF0000u);
    acc2 += e0.z * __uint_as_float(uA.y << 16) + e1.z * __uint_as_float(uB.y << 16) +
            e2.z * __uint_as_float(uC.y << 16) + e3.z * __uint_as_float(uD.y << 16);
    acc3 += e0.w * __uint_as_float(uA.y & 0xFFFF0000u) + e1.w * __uint_as_float(uB.y & 0xFFFF0000u) +
            e2.w * __uint_as_float(uC.y & 0xFFFF0000u) + e3.w * __uint_as_float(uD.y & 0xFFFF0000u);
    s0 += e0.x + e1.x + e2.x + e3.x;
    s1 += e0.y + e1.y + e2.y + e3.y;
    s2 += e0.z + e1.z + e2.z + e3.z;
    s3 += e0.w + e1.w + e2.w + e3.w;
  }
  for (; i < deg; ++i) {
    int sA = ssrc[start + i];
    float4 e0 = *(const float4*)(sex + (size_t)(start + i) * H);
    uint2 uA = *(const uint2*)(xlb + (size_t)sA * 256 + lane * 4);
    acc0 += e0.x * __uint_as_float(uA.x << 16);
    acc1 += e0.y * __uint_as_float(uA.x & 0xFFFF0000u);
    acc2 += e0.z * __uint_as_float(uA.y << 16);
    acc3 += e0.w * __uint_as_float(uA.y & 0xFFFF0000u);
    s0 += e0.x; s1 += e0.y; s2 += e0.z; s3 += e0.w;
  }
  float best = acc0 / (s0 + 1e-16f);
  best = fmaxf(best, acc1 / (s1 + 1e-16f));
  best = fmaxf(best, acc2 / (s2 + 1e-16f));
  best = fmaxf(best, acc3 / (s3 + 1e-16f));
  out[(size_t)wv * DOUT + lane] = fmaxf(best + nbias[lane], 0.f);
}

// ---------------- launcher -------------------------------------------------
extern "C" void kernel_launch(void* const* d_in, const int* in_sizes, int n_in,
                              void* d_out, int out_size, void* d_ws, size_t ws_size,
                              hipStream_t stream) {
  const float* x     = (const float*)d_in[0];
  const float* ea    = (const float*)d_in[1];
  const int*   ei    = (const int*)d_in[2];
  const float* Wl    = (const float*)d_in[3];
  const float* We    = (const float*)d_in[4];
  const float* att_l = (const float*)d_in[5];
  const float* att_r = (const float*)d_in[6];
  const float* att_e = (const float*)d_in[7];
  const float* nbias = (const float*)d_in[8];
  const float* ebias = (const float*)d_in[9];

  int N = in_sizes[0] / DIN;
  int E = in_sizes[1] / EIN;

  float* out  = (float*)d_out;
  float* eout = (float*)d_out + (size_t)N * DOUT;

  char* w = (char*)d_ws;
  auto alloc = [&](size_t bytes) -> void* {
    void* p = (void*)w;
    w += (bytes + 255) & ~(size_t)255;
    return p;
  };
  ushortT* xlb = (ushortT*)alloc((size_t)N * 256 * 2);
  float* al    = (float*)alloc((size_t)N * H * 4);
  float* ar    = (float*)alloc((size_t)N * H * 4);
  int* cnt     = (int*)alloc((size_t)N * 4);
  int* offs    = (int*)alloc((size_t)N * 4);
  int* cur     = (int*)alloc((size_t)N * 4);
  int* bsum    = (int*)alloc(256 * 4);
  int* boffs   = (int*)alloc(256 * 4);
  int* ssrc    = (int*)alloc((size_t)E * 4);
  float* sex   = (float*)alloc((size_t)E * H * 4);

  hipMemsetAsync(cnt, 0, (size_t)N * 4, stream);

  k_nodeproj<<<(N + 63) / 64, 256, 0, stream>>>(x, Wl, att_l, att_r, ei + E, cnt,
                                                xlb, al, ar, N, E);
  int NB = (N + 255) / 256;
  k_scan1<<<NB, 256, 0, stream>>>(cnt, offs, bsum, N);
  k_scan2<<<1, 256, 0, stream>>>(bsum, boffs, NB);
  k_scan3<<<NB, 256, 0, stream>>>(offs, boffs, cur, N);
  k_edgemfma<<<(E + 255) / 256, 256, 0, stream>>>(ea, We, att_e, ebias, ei, al, ar,
                                                  cur, eout, ssrc, sex, E);
  k_agg<<<(N * 64 + 255) / 256, 256, 0, stream>>>(xlb, ssrc, sex, offs, cnt,
                                                  nbias, out, N);
}